// Round 1
// baseline (869.815 us; speedup 1.0000x reference)
//
#include <hip/hip_runtime.h>
#include <hip/hip_bf16.h>

#define NN 49
#define CC 128
#define HH 4
#define HDIM 32
#define NWIN 64
#define BB 4096
#define SXS 136  // padded bf16 stride for s_x so rows stay 16B-aligned
#define QSCALE 0.17677669529663687f

// ---------- bf16 helpers (storage only; all math in f32) ----------
__device__ __forceinline__ unsigned short f2b(float f) {
    unsigned int x = __float_as_uint(f);
    return (unsigned short)((x + 0x7fffu + ((x >> 16) & 1u)) >> 16); // RNE
}
__device__ __forceinline__ void u2f2(unsigned int u, float& lo, float& hi) {
    lo = __uint_as_float(u << 16);
    hi = __uint_as_float(u & 0xffff0000u);
}
__device__ __forceinline__ float dot8(uint4 d, const float* wv, float acc) {
    float a, b;
    u2f2(d.x, a, b); acc = fmaf(a, wv[0], acc); acc = fmaf(b, wv[1], acc);
    u2f2(d.y, a, b); acc = fmaf(a, wv[2], acc); acc = fmaf(b, wv[3], acc);
    u2f2(d.z, a, b); acc = fmaf(a, wv[4], acc); acc = fmaf(b, wv[5], acc);
    u2f2(d.w, a, b); acc = fmaf(a, wv[6], acc); acc = fmaf(b, wv[7], acc);
    return acc;
}
__device__ __forceinline__ void exp8(uint4 d, float* f) {
    u2f2(d.x, f[0], f[1]); u2f2(d.y, f[2], f[3]);
    u2f2(d.z, f[4], f[5]); u2f2(d.w, f[6], f[7]);
}

// ---------- kernel 0: cb[w][h][i][m] = bias_table[rel_idx[i*49+m]][h] + mask[w][i][m] ----------
__global__ void bias_combine(const float* __restrict__ bias_table,
                             const int* __restrict__ rel_idx,
                             const float* __restrict__ mask,
                             float* __restrict__ cb) {
    int idx = blockIdx.x * blockDim.x + threadIdx.x;
    const int total = NWIN * HH * NN * NN;
    if (idx >= total) return;
    int r  = idx % (NN * NN);
    int wh = idx / (NN * NN);
    int h  = wh & (HH - 1);
    int w  = wh >> 2;
    cb[idx] = bias_table[rel_idx[r] * HH + h] + mask[w * NN * NN + r];
}

// ---------- staging: f32 global row-block -> bf16 LDS ----------
__device__ __forceinline__ void stage_bf16(const float* __restrict__ src,
                                           unsigned short* dst, int t) {
    const float4* s4 = (const float4*)src;
    #pragma unroll
    for (int rep = 0; rep < 7; ++rep) {
        int i = t + rep * 256;
        if (i < (NN * CC) / 4) {
            float4 v = s4[i];
            ushort4 u;
            u.x = f2b(v.x); u.y = f2b(v.y); u.z = f2b(v.z); u.w = f2b(v.w);
            *(ushort4*)(dst + 4 * i) = u;
        }
    }
}

// ---------- GEMM (49x128 in LDS) x (128xWSTRIDE-col-slice in global) -> bf16 LDS ----------
template<int WSTRIDE>
__device__ __forceinline__ void gemm_to_lds(const unsigned short* __restrict__ s_in,
                                            const float* __restrict__ wmat,
                                            float bias, float scale,
                                            unsigned short* __restrict__ s_out,
                                            int j, int g) {
    float acc[25];
    #pragma unroll
    for (int r = 0; r < 25; ++r) acc[r] = 0.f;
    #pragma unroll 2
    for (int ks = 0; ks < CC; ks += 8) {
        float wv[8];
        #pragma unroll
        for (int i = 0; i < 8; ++i) wv[i] = wmat[(ks + i) * WSTRIDE + j];
        #pragma unroll
        for (int r = 0; r < 25; ++r) {
            int n = 2 * r + g;
            if (n < NN) {
                uint4 d = *(const uint4*)(s_in + n * CC + ks);
                acc[r] = dot8(d, wv, acc[r]);
            }
        }
    }
    #pragma unroll
    for (int r = 0; r < 25; ++r) {
        int n = 2 * r + g;
        if (n < NN) s_out[n * CC + j] = f2b((acc[r] + bias) * scale);
    }
}

// ---------- final GEMM: (49x128 bf16 LDS, stride SXS) x proj_w -> f32 global ----------
__device__ __forceinline__ void gemm_out(const unsigned short* __restrict__ s_x,
                                         const float* __restrict__ wmat,
                                         float bias, float* __restrict__ outp,
                                         int j, int g) {
    float acc[25];
    #pragma unroll
    for (int r = 0; r < 25; ++r) acc[r] = 0.f;
    #pragma unroll 2
    for (int ks = 0; ks < CC; ks += 8) {
        float wv[8];
        #pragma unroll
        for (int i = 0; i < 8; ++i) wv[i] = wmat[(ks + i) * CC + j];
        #pragma unroll
        for (int r = 0; r < 25; ++r) {
            int n = 2 * r + g;
            if (n < NN) {
                uint4 d = *(const uint4*)(s_x + n * SXS + ks);
                acc[r] = dot8(d, wv, acc[r]);
            }
        }
    }
    #pragma unroll
    for (int r = 0; r < 25; ++r) {
        int n = 2 * r + g;
        if (n < NN) outp[n * CC + j] = acc[r] + bias;
    }
}

// ---------- main fused kernel: one block per window ----------
__global__ __launch_bounds__(256, 2)
void wmha_main(const float* __restrict__ query, const float* __restrict__ source,
               const float* __restrict__ q_w, const float* __restrict__ q_b,
               const float* __restrict__ kv_w, const float* __restrict__ kv_b,
               const float* __restrict__ proj_w, const float* __restrict__ proj_b,
               const float* __restrict__ cb, float* __restrict__ out) {
    __shared__ unsigned short s_a[NN * CC];   // input staging (query, then source)
    __shared__ unsigned short s_q[NN * CC];   // scaled q projection
    __shared__ unsigned short s_k[NN * CC];
    __shared__ unsigned short s_v[NN * CC];
    __shared__ unsigned short s_x[NN * SXS];  // attention output

    const int t = threadIdx.x;
    const int b = blockIdx.x;
    const int j = t & (CC - 1);
    const int g = t >> 7;              // 0: even rows, 1: odd rows
    const int wmask = b & (NWIN - 1);  // window index for mask/bias table

    // q = (query @ q_w + q_b) * scale
    stage_bf16(query + (size_t)b * NN * CC, s_a, t);
    __syncthreads();
    gemm_to_lds<CC>(s_a, q_w, q_b[j], QSCALE, s_q, j, g);
    __syncthreads();

    // k = kv[..., :C], v = kv[..., C:]
    stage_bf16(source + (size_t)b * NN * CC, s_a, t);
    __syncthreads();
    gemm_to_lds<2 * CC>(s_a, kv_w,      kv_b[j],      1.0f, s_k, j, g);
    gemm_to_lds<2 * CC>(s_a, kv_w + CC, kv_b[CC + j], 1.0f, s_v, j, g);
    __syncthreads();

    // attention: one wave per head, lane = query row
    {
        const int lane = t & 63;
        const int h = t >> 6;
        if (lane < NN) {
            const int i = lane;
            // q row -> registers
            float qf[HDIM];
            #pragma unroll
            for (int dd = 0; dd < HDIM; dd += 8) {
                uint4 d = *(const uint4*)(s_q + i * CC + h * HDIM + dd);
                exp8(d, qf + dd);
            }
            const float* cbrow = cb + ((size_t)((wmask * HH + h) * NN + i)) * NN;
            // logits
            float p[NN];
            #pragma unroll
            for (int m = 0; m < NN; ++m) {
                float acc = cbrow[m];
                const unsigned short* kr = s_k + m * CC + h * HDIM;  // lane-uniform -> broadcast
                #pragma unroll
                for (int dd = 0; dd < HDIM; dd += 8) {
                    uint4 d = *(const uint4*)(kr + dd);
                    acc = dot8(d, qf + dd, acc);
                }
                p[m] = acc;
            }
            // softmax (exact, max-subtracted)
            float mx = p[0];
            #pragma unroll
            for (int m = 1; m < NN; ++m) mx = fmaxf(mx, p[m]);
            float sum = 0.f;
            #pragma unroll
            for (int m = 0; m < NN; ++m) { p[m] = __expf(p[m] - mx); sum += p[m]; }
            float inv = 1.f / sum;
            // x = p @ v
            float xv[HDIM];
            #pragma unroll
            for (int dd = 0; dd < HDIM; ++dd) xv[dd] = 0.f;
            #pragma unroll
            for (int m = 0; m < NN; ++m) {
                const unsigned short* vr = s_v + m * CC + h * HDIM;  // broadcast
                float pm = p[m];
                #pragma unroll
                for (int dd = 0; dd < HDIM; dd += 8) {
                    uint4 d = *(const uint4*)(vr + dd);
                    float f[8]; exp8(d, f);
                    #pragma unroll
                    for (int q2 = 0; q2 < 8; ++q2) xv[dd + q2] = fmaf(pm, f[q2], xv[dd + q2]);
                }
            }
            // write x (normalized) to s_x
            unsigned short* xr = s_x + i * SXS + h * HDIM;
            #pragma unroll
            for (int dd = 0; dd < HDIM; dd += 2) {
                unsigned int pk = ((unsigned int)f2b(xv[dd + 1] * inv) << 16)
                                |  (unsigned int)f2b(xv[dd] * inv);
                *(unsigned int*)(xr + dd) = pk;
            }
        }
    }
    __syncthreads();

    // out = x @ proj_w + proj_b
    gemm_out(s_x, proj_w, proj_b[j], out + (size_t)b * NN * CC, j, g);
}

extern "C" void kernel_launch(void* const* d_in, const int* in_sizes, int n_in,
                              void* d_out, int out_size, void* d_ws, size_t ws_size,
                              hipStream_t stream) {
    const float* query      = (const float*)d_in[0];
    const float* source     = (const float*)d_in[1];
    const float* mask       = (const float*)d_in[2];
    const float* q_w        = (const float*)d_in[3];
    const float* q_b        = (const float*)d_in[4];
    const float* kv_w       = (const float*)d_in[5];
    const float* kv_b       = (const float*)d_in[6];
    const float* proj_w     = (const float*)d_in[7];
    const float* proj_b     = (const float*)d_in[8];
    const float* bias_table = (const float*)d_in[9];
    const int*   rel_idx    = (const int*)d_in[10];
    float* out = (float*)d_out;
    float* cb  = (float*)d_ws;  // NWIN*HH*NN*NN f32 = 2.46 MB

    const int total = NWIN * HH * NN * NN;
    bias_combine<<<(total + 255) / 256, 256, 0, stream>>>(bias_table, rel_idx, mask, cb);
    wmha_main<<<BB, 256, 0, stream>>>(query, source, q_w, q_b, kv_w, kv_b,
                                      proj_w, proj_b, cb, out);
}

// Round 2
// 135.724 us; speedup vs baseline: 6.4087x; 6.4087x over previous
//
#include <hip/hip_runtime.h>

#define NN 49
#define CC 128
#define HH 4
#define NWIN 64
#define BB 4096
#define QSCALE 0.17677669529663687f

typedef __attribute__((ext_vector_type(8))) short bf16x8;
typedef __attribute__((ext_vector_type(4))) float f32x4;
typedef unsigned short u16;
typedef unsigned int u32;

__device__ __forceinline__ u16 f2b(float f) {
    u32 x = __float_as_uint(f);
    return (u16)((x + 0x7fffu + ((x >> 16) & 1u)) >> 16);  // RNE
}
__device__ __forceinline__ float b2f(u16 u) { return __uint_as_float(((u32)u) << 16); }
__device__ __forceinline__ uint2 pack4(float a, float b, float c, float d) {
    uint2 r;
    r.x = (u32)f2b(a) | ((u32)f2b(b) << 16);
    r.y = (u32)f2b(c) | ((u32)f2b(d) << 16);
    return r;
}
__device__ __forceinline__ f32x4 mfma16(bf16x8 a, bf16x8 b, f32x4 c) {
    return __builtin_amdgcn_mfma_f32_16x16x32_bf16(a, b, c, 0, 0, 0);
}
// XOR-swizzled byte address inside a row-major LDS tile (m214 pattern)
__device__ __forceinline__ char* adr256(u16* base, int row, int byte) {
    return (char*)base + row * 256 + (byte ^ ((row & 7) << 4));
}
__device__ __forceinline__ char* adr128(u16* base, int row, int byte) {
    return (char*)base + row * 128 + (byte ^ ((row & 7) << 4));
}

// ---- prep 1: cb_t[w][h][i][m] = bias[rel[i,m]][h] + mask[w][i][m]  (bf16, -1e9 pads) ----
__global__ void prep_cbt(const float* __restrict__ bias_table, const int* __restrict__ rel_idx,
                         const float* __restrict__ mask, u16* __restrict__ cbt) {
    int idx = blockIdx.x * blockDim.x + threadIdx.x;
    int m = idx & 63, i = (idx >> 6) & 63, h = (idx >> 12) & 3, wv = idx >> 14;
    if (wv >= NWIN) return;
    float v = -1e9f;
    if (m < NN && i < NN)
        v = bias_table[rel_idx[i * NN + m] * HH + h] + mask[(wv * NN + i) * NN + m];
    cbt[idx] = f2b(v);
}

// ---- prep 2: pack weights into exact B-fragment layout, bf16 ----
// packed[nt][kt][lane][i] = W[32kt + 8*(lane>>4) + i][16nt + (lane&15)]
__global__ void prep_w(const float* __restrict__ qw, const float* __restrict__ qb,
                       const float* __restrict__ kvw, const float* __restrict__ pjw,
                       u16* __restrict__ qwp, u16* __restrict__ kvwp,
                       u16* __restrict__ pjwp, float* __restrict__ qbs) {
    int idx = blockIdx.x * blockDim.x + threadIdx.x;
    if (idx < 16384) {
        int i = idx & 7, lane = (idx >> 3) & 63, kt = (idx >> 9) & 3, nt = idx >> 11;
        int k = 32 * kt + 8 * (lane >> 4) + i, n = 16 * nt + (lane & 15);
        qwp[idx] = f2b(qw[k * CC + n] * QSCALE);
    } else if (idx < 49152) {
        int j = idx - 16384;
        int i = j & 7, lane = (j >> 3) & 63, kt = (j >> 9) & 3, nt = j >> 11;
        int k = 32 * kt + 8 * (lane >> 4) + i, n = 16 * nt + (lane & 15);
        kvwp[j] = f2b(kvw[k * 2 * CC + n]);
    } else if (idx < 65536) {
        int j = idx - 49152;
        int i = j & 7, lane = (j >> 3) & 63, kt = (j >> 9) & 3, nt = j >> 11;
        int k = 32 * kt + 8 * (lane >> 4) + i, n = 16 * nt + (lane & 15);
        pjwp[j] = f2b(pjw[k * CC + n]);
    } else if (idx < 65664) {
        int j = idx - 65536;
        qbs[j] = qb[j] * QSCALE;
    }
}

// ---- main fused kernel: one block per window, 4 waves, full MFMA path ----
__global__ __launch_bounds__(256, 2)
void wmha_main(const float* __restrict__ query, const float* __restrict__ source,
               const u16* __restrict__ qwp, const u16* __restrict__ kvwp,
               const u16* __restrict__ pjwp, const float* __restrict__ qbs,
               const float* __restrict__ kv_b, const float* __restrict__ proj_b,
               const u16* __restrict__ cbt, float* __restrict__ out) {
    __shared__ u16 lds[32768];              // 64 KB, 4 x 16KB regions
    u16* R0 = lds;                          // staged query -> P heads 0,1
    u16* R1 = lds + 8192;                   // staged source -> v^T
    u16* R2 = lds + 16384;                  // q -> P heads 2,3
    u16* R3 = lds + 24576;                  // k -> x
    const int t = threadIdx.x;
    const int b = blockIdx.x;
    const int w = t >> 6, lane = t & 63;
    const int lq = lane & 15, qd = lane >> 4;

    // ---- stage query->R0, source->R1 (bf16, zero-pad rows 49..63, swizzled) ----
    {
        const int row = t >> 2, qu = t & 3;
        const size_t gbase = (size_t)b * NN * CC + row * CC + qu * 32;
        #pragma unroll
        for (int j = 0; j < 4; ++j) {
            bf16x8 vq = {0,0,0,0,0,0,0,0}, vs = {0,0,0,0,0,0,0,0};
            if (row < NN) {
                const float4* q4 = (const float4*)(query + gbase) + 2 * j;
                const float4* s4 = (const float4*)(source + gbase) + 2 * j;
                float4 a0 = q4[0], a1 = q4[1], c0 = s4[0], c1 = s4[1];
                vq[0]=(short)f2b(a0.x); vq[1]=(short)f2b(a0.y); vq[2]=(short)f2b(a0.z); vq[3]=(short)f2b(a0.w);
                vq[4]=(short)f2b(a1.x); vq[5]=(short)f2b(a1.y); vq[6]=(short)f2b(a1.z); vq[7]=(short)f2b(a1.w);
                vs[0]=(short)f2b(c0.x); vs[1]=(short)f2b(c0.y); vs[2]=(short)f2b(c0.z); vs[3]=(short)f2b(c0.w);
                vs[4]=(short)f2b(c1.x); vs[5]=(short)f2b(c1.y); vs[6]=(short)f2b(c1.z); vs[7]=(short)f2b(c1.w);
            }
            *(bf16x8*)adr256(R0, row, qu * 64 + 16 * j) = vq;
            *(bf16x8*)adr256(R1, row, qu * 64 + 16 * j) = vs;
        }
    }
    __syncthreads();  // B0: inputs staged

    // ---- GEMM1: q = Xq @ qw_scaled  (wave w -> nt = w, w+4) -> R2 ----
    {
        bf16x8 bw[2][4];
        #pragma unroll
        for (int n2 = 0; n2 < 2; ++n2)
            #pragma unroll
            for (int kt = 0; kt < 4; ++kt)
                bw[n2][kt] = *(const bf16x8*)(qwp + (((w + 4 * n2) * 4 + kt) * 64 + lane) * 8);
        f32x4 acc[4][2] = {};
        #pragma unroll
        for (int mt = 0; mt < 4; ++mt) {
            bf16x8 a[4];
            #pragma unroll
            for (int kt = 0; kt < 4; ++kt)
                a[kt] = *(const bf16x8*)adr256(R0, mt * 16 + lq, kt * 64 + qd * 16);
            #pragma unroll
            for (int n2 = 0; n2 < 2; ++n2)
                #pragma unroll
                for (int kt = 0; kt < 4; ++kt)
                    acc[mt][n2] = mfma16(a[kt], bw[n2][kt], acc[mt][n2]);
        }
        #pragma unroll
        for (int n2 = 0; n2 < 2; ++n2) {
            const int col = 16 * (w + 4 * n2) + lq;
            const float bias = qbs[col];
            #pragma unroll
            for (int mt = 0; mt < 4; ++mt)
                #pragma unroll
                for (int r = 0; r < 4; ++r) {
                    const int row = mt * 16 + qd * 4 + r;
                    *(u16*)adr256(R2, row, 2 * col) = f2b(acc[mt][n2][r] + bias);
                }
        }
    }

    // ---- GEMM2: kv = Xs @ kvw  (nt = w,w+4 -> k in R3; nt = w+8,w+12 -> v^T in R1) ----
    {
        bf16x8 bw[4][4];
        #pragma unroll
        for (int n4 = 0; n4 < 4; ++n4)
            #pragma unroll
            for (int kt = 0; kt < 4; ++kt)
                bw[n4][kt] = *(const bf16x8*)(kvwp + (((w + 4 * n4) * 4 + kt) * 64 + lane) * 8);
        f32x4 acc[4][4] = {};
        #pragma unroll
        for (int mt = 0; mt < 4; ++mt) {
            bf16x8 a[4];
            #pragma unroll
            for (int kt = 0; kt < 4; ++kt)
                a[kt] = *(const bf16x8*)adr256(R1, mt * 16 + lq, kt * 64 + qd * 16);
            #pragma unroll
            for (int n4 = 0; n4 < 4; ++n4)
                #pragma unroll
                for (int kt = 0; kt < 4; ++kt)
                    acc[mt][n4] = mfma16(a[kt], bw[n4][kt], acc[mt][n4]);
        }
        // k epilogue -> R3 (R3 untouched so far: safe pre-barrier)
        #pragma unroll
        for (int n4 = 0; n4 < 2; ++n4) {
            const int col = 16 * (w + 4 * n4) + lq;
            const float bias = kv_b[col];
            #pragma unroll
            for (int mt = 0; mt < 4; ++mt)
                #pragma unroll
                for (int r = 0; r < 4; ++r) {
                    const int row = mt * 16 + qd * 4 + r;
                    *(u16*)adr256(R3, row, 2 * col) = f2b(acc[mt][n4][r] + bias);
                }
        }
        __syncthreads();  // B1: all reads of R0/R1 done; q,k complete in LDS
        // v^T epilogue -> R1: v_t[dim][key]  (D rows are consecutive keys -> b64 writes)
        #pragma unroll
        for (int n4 = 2; n4 < 4; ++n4) {
            const int dim = 16 * w + 64 * (n4 - 2) + lq;
            const float bias = kv_b[CC + dim];
            #pragma unroll
            for (int mt = 0; mt < 4; ++mt) {
                uint2 pk = pack4(acc[mt][n4][0] + bias, acc[mt][n4][1] + bias,
                                 acc[mt][n4][2] + bias, acc[mt][n4][3] + bias);
                *(uint2*)adr128(R1, dim, 2 * (mt * 16 + qd * 4)) = pk;
            }
        }
    }

    // ---- attention: wave w = head h; S^T = K·Q^T (swapped operands) ----
    const int h = w;
    f32x4 s[4][4];       // [query tile][key tile]
    uint2 cb2[4][4];
    float inv[4];
    u16* ph = (w < 2 ? R0 : R2) + (w & 1) * 4096;  // per-head P buffer [64][64] bf16
    {
        bf16x8 kf[4], qf[4];
        #pragma unroll
        for (int a = 0; a < 4; ++a)
            kf[a] = *(const bf16x8*)adr256(R3, a * 16 + lq, h * 64 + qd * 16);
        #pragma unroll
        for (int bq = 0; bq < 4; ++bq)
            qf[bq] = *(const bf16x8*)adr256(R2, bq * 16 + lq, h * 64 + qd * 16);
        const u16* cbb = cbt + (((size_t)((b & (NWIN - 1)) * HH + h)) << 12);
        #pragma unroll
        for (int bq = 0; bq < 4; ++bq)
            #pragma unroll
            for (int a = 0; a < 4; ++a)
                cb2[bq][a] = *(const uint2*)(cbb + (bq * 16 + lq) * 64 + a * 16 + qd * 4);
        #pragma unroll
        for (int bq = 0; bq < 4; ++bq) {
            f32x4 z = {0.f, 0.f, 0.f, 0.f};
            #pragma unroll
            for (int a = 0; a < 4; ++a)
                s[bq][a] = mfma16(kf[a], qf[bq], z);
        }
    }
    __syncthreads();  // B2: q(R2)/k(R3) reads done by all waves; v^T visible

    #pragma unroll
    for (int bq = 0; bq < 4; ++bq) {
        #pragma unroll
        for (int a = 0; a < 4; ++a) {
            s[bq][a][0] += b2f((u16)(cb2[bq][a].x & 0xffffu));
            s[bq][a][1] += b2f((u16)(cb2[bq][a].x >> 16));
            s[bq][a][2] += b2f((u16)(cb2[bq][a].y & 0xffffu));
            s[bq][a][3] += b2f((u16)(cb2[bq][a].y >> 16));
        }
        float m0 = s[bq][0][0];
        #pragma unroll
        for (int a = 0; a < 4; ++a)
            #pragma unroll
            for (int r = 0; r < 4; ++r) m0 = fmaxf(m0, s[bq][a][r]);
        m0 = fmaxf(m0, __shfl_xor(m0, 16));
        m0 = fmaxf(m0, __shfl_xor(m0, 32));
        float sm = 0.f;
        const int prow = bq * 16 + lq;
        #pragma unroll
        for (int a = 0; a < 4; ++a) {
            u16 p0 = f2b(__expf(s[bq][a][0] - m0));
            u16 p1 = f2b(__expf(s[bq][a][1] - m0));
            u16 p2 = f2b(__expf(s[bq][a][2] - m0));
            u16 p3 = f2b(__expf(s[bq][a][3] - m0));
            sm += b2f(p0) + b2f(p1) + b2f(p2) + b2f(p3);  // normalize by bf16-rounded sum
            uint2 pk;
            pk.x = (u32)p0 | ((u32)p1 << 16);
            pk.y = (u32)p2 | ((u32)p3 << 16);
            *(uint2*)adr128(ph, prow, 2 * (a * 16 + qd * 4)) = pk;
        }
        sm += __shfl_xor(sm, 16);
        sm += __shfl_xor(sm, 32);
        inv[bq] = 1.f / sm;
    }

    // ---- PV: O^T = V^T · P^T -> x[query][dim] in R3 ----
    {
        f32x4 o[2][4] = {};
        bf16x8 vf[2][2];
        #pragma unroll
        for (int dt = 0; dt < 2; ++dt)
            #pragma unroll
            for (int kt = 0; kt < 2; ++kt)
                vf[dt][kt] = *(const bf16x8*)adr128(R1, h * 32 + dt * 16 + lq, kt * 64 + qd * 16);
        #pragma unroll
        for (int bq = 0; bq < 4; ++bq)
            #pragma unroll
            for (int kt = 0; kt < 2; ++kt) {
                bf16x8 pf = *(const bf16x8*)adr128(ph, bq * 16 + lq, kt * 64 + qd * 16);
                #pragma unroll
                for (int dt = 0; dt < 2; ++dt)
                    o[dt][bq] = mfma16(vf[dt][kt], pf, o[dt][bq]);
            }
        #pragma unroll
        for (int bq = 0; bq < 4; ++bq)
            #pragma unroll
            for (int dt = 0; dt < 2; ++dt) {
                const int row = bq * 16 + lq;  // query
                uint2 pk = pack4(o[dt][bq][0] * inv[bq], o[dt][bq][1] * inv[bq],
                                 o[dt][bq][2] * inv[bq], o[dt][bq][3] * inv[bq]);
                *(uint2*)adr256(R3, row, 2 * (h * 32 + dt * 16 + qd * 4)) = pk;
            }
    }

    // ---- GEMM3: out = x @ pjw + proj_b ----
    {
        bf16x8 bw[2][4];
        #pragma unroll
        for (int n2 = 0; n2 < 2; ++n2)
            #pragma unroll
            for (int kt = 0; kt < 4; ++kt)
                bw[n2][kt] = *(const bf16x8*)(pjwp + (((w + 4 * n2) * 4 + kt) * 64 + lane) * 8);
        __syncthreads();  // B3: x complete (B-frags prefetched above the barrier)
        f32x4 acc[4][2] = {};
        #pragma unroll
        for (int mt = 0; mt < 4; ++mt) {
            bf16x8 a[4];
            #pragma unroll
            for (int kt = 0; kt < 4; ++kt)
                a[kt] = *(const bf16x8*)adr256(R3, mt * 16 + lq, kt * 64 + qd * 16);
            #pragma unroll
            for (int n2 = 0; n2 < 2; ++n2)
                #pragma unroll
                for (int kt = 0; kt < 4; ++kt)
                    acc[mt][n2] = mfma16(a[kt], bw[n2][kt], acc[mt][n2]);
        }
        float* outb = out + (size_t)b * NN * CC;
        #pragma unroll
        for (int n2 = 0; n2 < 2; ++n2) {
            const int col = 16 * (w + 4 * n2) + lq;
            const float bias = proj_b[col];
            #pragma unroll
            for (int mt = 0; mt < 4; ++mt)
                #pragma unroll
                for (int r = 0; r < 4; ++r) {
                    const int row = mt * 16 + qd * 4 + r;
                    if (row < NN) outb[row * CC + col] = acc[mt][n2][r] + bias;
                }
        }
    }
}

extern "C" void kernel_launch(void* const* d_in, const int* in_sizes, int n_in,
                              void* d_out, int out_size, void* d_ws, size_t ws_size,
                              hipStream_t stream) {
    const float* query      = (const float*)d_in[0];
    const float* source     = (const float*)d_in[1];
    const float* mask       = (const float*)d_in[2];
    const float* q_w        = (const float*)d_in[3];
    const float* q_b        = (const float*)d_in[4];
    const float* kv_w       = (const float*)d_in[5];
    const float* kv_b       = (const float*)d_in[6];
    const float* proj_w     = (const float*)d_in[7];
    const float* proj_b     = (const float*)d_in[8];
    const float* bias_table = (const float*)d_in[9];
    const int*   rel_idx    = (const int*)d_in[10];
    float* out = (float*)d_out;

    u16* cbt   = (u16*)d_ws;           // 1 Mi u16 = 2 MB
    u16* qwp   = cbt + 1048576;        // 16384 u16
    u16* kvwp  = qwp + 16384;          // 32768 u16
    u16* pjwp  = kvwp + 32768;         // 16384 u16
    float* qbs = (float*)(pjwp + 16384);  // 128 f32

    prep_cbt<<<4096, 256, 0, stream>>>(bias_table, rel_idx, mask, cbt);
    prep_w<<<257, 256, 0, stream>>>(q_w, q_b, kv_w, proj_w, qwp, kvwp, pjwp, qbs);
    wmha_main<<<BB, 256, 0, stream>>>(query, source, qwp, kvwp, pjwp, qbs,
                                      kv_b, proj_b, cbt, out);
}

// Round 4
// 125.306 us; speedup vs baseline: 6.9415x; 1.0831x over previous
//
#include <hip/hip_runtime.h>

#define NN 49
#define CC 128
#define HH 4
#define NWIN 64
#define BB 4096
#define QSCALE 0.17677669529663687f

typedef __attribute__((ext_vector_type(8))) short bf16x8;
typedef __attribute__((ext_vector_type(4))) float f32x4;
typedef unsigned short u16;
typedef unsigned int u32;

__device__ __forceinline__ u16 f2b(float f) {
    u32 x = __float_as_uint(f);
    return (u16)((x + 0x7fffu + ((x >> 16) & 1u)) >> 16);  // RNE
}
__device__ __forceinline__ float b2f(u16 u) { return __uint_as_float(((u32)u) << 16); }
__device__ __forceinline__ uint2 pack4(float a, float b, float c, float d) {
    uint2 r;
    r.x = (u32)f2b(a) | ((u32)f2b(b) << 16);
    r.y = (u32)f2b(c) | ((u32)f2b(d) << 16);
    return r;
}
__device__ __forceinline__ f32x4 mfma16(bf16x8 a, bf16x8 b, f32x4 c) {
    return __builtin_amdgcn_mfma_f32_16x16x32_bf16(a, b, c, 0, 0, 0);
}
// XOR-swizzled byte address inside a row-major LDS tile
__device__ __forceinline__ char* adr256(u16* base, int row, int byte) {
    return (char*)base + row * 256 + (byte ^ ((row & 7) << 4));
}
__device__ __forceinline__ char* adr128(u16* base, int row, int byte) {
    return (char*)base + row * 128 + (byte ^ ((row & 7) << 4));
}

// ---- prep 1: cb_t[w][h][i][m] = bias[rel[i,m]][h] + mask[w][i][m]  (bf16, -1e9 pads) ----
__global__ void prep_cbt(const float* __restrict__ bias_table, const int* __restrict__ rel_idx,
                         const float* __restrict__ mask, u16* __restrict__ cbt) {
    int idx = blockIdx.x * blockDim.x + threadIdx.x;
    int m = idx & 63, i = (idx >> 6) & 63, h = (idx >> 12) & 3, wv = idx >> 14;
    if (wv >= NWIN) return;
    float v = -1e9f;
    if (m < NN && i < NN)
        v = bias_table[rel_idx[i * NN + m] * HH + h] + mask[(wv * NN + i) * NN + m];
    cbt[idx] = f2b(v);
}

// ---- prep 2: pack weights into exact B-fragment layout, bf16 ----
// packed[nt][kt][lane][i] = W[32kt + 8*(lane>>4) + i][16nt + (lane&15)]
__global__ void prep_w(const float* __restrict__ qw, const float* __restrict__ qb,
                       const float* __restrict__ kvw, const float* __restrict__ pjw,
                       u16* __restrict__ qwp, u16* __restrict__ kvwp,
                       u16* __restrict__ pjwp, float* __restrict__ qbs) {
    int idx = blockIdx.x * blockDim.x + threadIdx.x;
    if (idx < 16384) {
        int i = idx & 7, lane = (idx >> 3) & 63, kt = (idx >> 9) & 3, nt = idx >> 11;
        int k = 32 * kt + 8 * (lane >> 4) + i, n = 16 * nt + (lane & 15);
        qwp[idx] = f2b(qw[k * CC + n] * QSCALE);
    } else if (idx < 49152) {
        int j = idx - 16384;
        int i = j & 7, lane = (j >> 3) & 63, kt = (j >> 9) & 3, nt = j >> 11;
        int k = 32 * kt + 8 * (lane >> 4) + i, n = 16 * nt + (lane & 15);
        kvwp[j] = f2b(kvw[k * 2 * CC + n]);
    } else if (idx < 65536) {
        int j = idx - 49152;
        int i = j & 7, lane = (j >> 3) & 63, kt = (j >> 9) & 3, nt = j >> 11;
        int k = 32 * kt + 8 * (lane >> 4) + i, n = 16 * nt + (lane & 15);
        pjwp[j] = f2b(pjw[k * CC + n]);
    } else if (idx < 65664) {
        int j = idx - 65536;
        qbs[j] = qb[j] * QSCALE;
    }
}

// ---- main fused kernel: one block per window, 4 waves, 48KB LDS, 3 blocks/CU ----
__global__ __launch_bounds__(256, 3)
void wmha_main(const float* __restrict__ query, const float* __restrict__ source,
               const u16* __restrict__ qwp, const u16* __restrict__ kvwp,
               const u16* __restrict__ pjwp, const float* __restrict__ qbs,
               const float* __restrict__ kv_b, const float* __restrict__ proj_b,
               const u16* __restrict__ cbt, float* __restrict__ out) {
    __shared__ u16 lds[24576];   // 48 KB
    u16* R0 = lds;               // Xq -> k -> per-wave P scratch
    u16* R1 = lds + 8192;        // q -> x
    u16* R2 = lds + 16384;       // Xs -> v^T
    const int t = threadIdx.x;
    const int b = blockIdx.x;
    const int w = t >> 6, lane = t & 63;
    const int lq = lane & 15, qd = lane >> 4;

    // ---- stage Xq->R0 and Xs->R2 (bf16, zero-pad rows 49..63, swizzled) ----
    {
        const int row = t >> 2, qu = t & 3;
        const size_t gbase = (size_t)b * NN * CC + row * CC + qu * 32;
        #pragma unroll
        for (int j = 0; j < 4; ++j) {
            bf16x8 vq = {0,0,0,0,0,0,0,0}, vs = {0,0,0,0,0,0,0,0};
            if (row < NN) {
                const float4* q4 = (const float4*)(query + gbase) + 2 * j;
                const float4* s4 = (const float4*)(source + gbase) + 2 * j;
                float4 a0 = q4[0], a1 = q4[1], c0 = s4[0], c1 = s4[1];
                vq[0]=(short)f2b(a0.x); vq[1]=(short)f2b(a0.y); vq[2]=(short)f2b(a0.z); vq[3]=(short)f2b(a0.w);
                vq[4]=(short)f2b(a1.x); vq[5]=(short)f2b(a1.y); vq[6]=(short)f2b(a1.z); vq[7]=(short)f2b(a1.w);
                vs[0]=(short)f2b(c0.x); vs[1]=(short)f2b(c0.y); vs[2]=(short)f2b(c0.z); vs[3]=(short)f2b(c0.w);
                vs[4]=(short)f2b(c1.x); vs[5]=(short)f2b(c1.y); vs[6]=(short)f2b(c1.z); vs[7]=(short)f2b(c1.w);
            }
            *(bf16x8*)adr256(R0, row, qu * 64 + 16 * j) = vq;
            *(bf16x8*)adr256(R2, row, qu * 64 + 16 * j) = vs;
        }
    }
    // GEMM1 B-frags prefetched pre-barrier
    bf16x8 bwq[2][4];
    #pragma unroll
    for (int n2 = 0; n2 < 2; ++n2)
        #pragma unroll
        for (int kt = 0; kt < 4; ++kt)
            bwq[n2][kt] = *(const bf16x8*)(qwp + (((w + 4 * n2) * 4 + kt) * 64 + lane) * 8);
    __syncthreads();  // bar0: inputs staged

    // ---- GEMM1: q = Xq @ qw_scaled -> R1 ----
    {
        f32x4 acc[4][2] = {};
        __builtin_amdgcn_s_setprio(1);
        #pragma unroll
        for (int mt = 0; mt < 4; ++mt) {
            bf16x8 a[4];
            #pragma unroll
            for (int kt = 0; kt < 4; ++kt)
                a[kt] = *(const bf16x8*)adr256(R0, mt * 16 + lq, kt * 64 + qd * 16);
            #pragma unroll
            for (int n2 = 0; n2 < 2; ++n2)
                #pragma unroll
                for (int kt = 0; kt < 4; ++kt)
                    acc[mt][n2] = mfma16(a[kt], bwq[n2][kt], acc[mt][n2]);
        }
        __builtin_amdgcn_s_setprio(0);
        #pragma unroll
        for (int n2 = 0; n2 < 2; ++n2) {
            const int col = 16 * (w + 4 * n2) + lq;
            const float bias = qbs[col];
            #pragma unroll
            for (int mt = 0; mt < 4; ++mt)
                #pragma unroll
                for (int r = 0; r < 4; ++r) {
                    const int row = mt * 16 + qd * 4 + r;
                    *(u16*)adr256(R1, row, 2 * col) = f2b(acc[mt][n2][r] + bias);
                }
        }
    }
    __syncthreads();  // bar1: all GEMM1 reads of R0 done

    // ---- GEMM2k: k = Xs @ kvw[:, :128] -> R0 ----
    {
        bf16x8 bw[2][4];
        #pragma unroll
        for (int n2 = 0; n2 < 2; ++n2)
            #pragma unroll
            for (int kt = 0; kt < 4; ++kt)
                bw[n2][kt] = *(const bf16x8*)(kvwp + (((w + 4 * n2) * 4 + kt) * 64 + lane) * 8);
        f32x4 acc[4][2] = {};
        __builtin_amdgcn_s_setprio(1);
        #pragma unroll
        for (int mt = 0; mt < 4; ++mt) {
            bf16x8 a[4];
            #pragma unroll
            for (int kt = 0; kt < 4; ++kt)
                a[kt] = *(const bf16x8*)adr256(R2, mt * 16 + lq, kt * 64 + qd * 16);
            #pragma unroll
            for (int n2 = 0; n2 < 2; ++n2)
                #pragma unroll
                for (int kt = 0; kt < 4; ++kt)
                    acc[mt][n2] = mfma16(a[kt], bw[n2][kt], acc[mt][n2]);
        }
        __builtin_amdgcn_s_setprio(0);
        #pragma unroll
        for (int n2 = 0; n2 < 2; ++n2) {
            const int col = 16 * (w + 4 * n2) + lq;
            const float bias = kv_b[col];
            #pragma unroll
            for (int mt = 0; mt < 4; ++mt)
                #pragma unroll
                for (int r = 0; r < 4; ++r) {
                    const int row = mt * 16 + qd * 4 + r;
                    *(u16*)adr256(R0, row, 2 * col) = f2b(acc[mt][n2][r] + bias);
                }
        }
    }

    // ---- GEMM2v: v = Xs @ kvw[:, 128:]  (acc held across bar2, then v^T -> R2) ----
    {
        bf16x8 bw[2][4];
        #pragma unroll
        for (int n2 = 0; n2 < 2; ++n2)
            #pragma unroll
            for (int kt = 0; kt < 4; ++kt)
                bw[n2][kt] = *(const bf16x8*)(kvwp + (((w + 8 + 4 * n2) * 4 + kt) * 64 + lane) * 8);
        f32x4 acc[4][2] = {};
        __builtin_amdgcn_s_setprio(1);
        #pragma unroll
        for (int mt = 0; mt < 4; ++mt) {
            bf16x8 a[4];
            #pragma unroll
            for (int kt = 0; kt < 4; ++kt)
                a[kt] = *(const bf16x8*)adr256(R2, mt * 16 + lq, kt * 64 + qd * 16);
            #pragma unroll
            for (int n2 = 0; n2 < 2; ++n2)
                #pragma unroll
                for (int kt = 0; kt < 4; ++kt)
                    acc[mt][n2] = mfma16(a[kt], bw[n2][kt], acc[mt][n2]);
        }
        __builtin_amdgcn_s_setprio(0);
        __syncthreads();  // bar2: k visible; all Xs (R2) reads done
        // v^T epilogue -> R2: v_t[dim][key]
        #pragma unroll
        for (int n2 = 0; n2 < 2; ++n2) {
            const int dim = 16 * w + 64 * n2 + lq;
            const float bias = kv_b[CC + dim];
            #pragma unroll
            for (int mt = 0; mt < 4; ++mt) {
                uint2 pk = pack4(acc[mt][n2][0] + bias, acc[mt][n2][1] + bias,
                                 acc[mt][n2][2] + bias, acc[mt][n2][3] + bias);
                *(uint2*)adr128(R2, dim, 2 * (mt * 16 + qd * 4)) = pk;
            }
        }
    }

    // ---- QK^T (swapped): S^T[key][query], head h = wave w ----
    const int h = w;
    f32x4 s[4][4];
    {
        bf16x8 kf[4];
        #pragma unroll
        for (int a = 0; a < 4; ++a)
            kf[a] = *(const bf16x8*)adr256(R0, a * 16 + lq, h * 64 + qd * 16);
        __builtin_amdgcn_s_setprio(1);
        #pragma unroll
        for (int bq = 0; bq < 4; ++bq) {
            bf16x8 qf = *(const bf16x8*)adr256(R1, bq * 16 + lq, h * 64 + qd * 16);
            f32x4 z = {0.f, 0.f, 0.f, 0.f};
            #pragma unroll
            for (int a = 0; a < 4; ++a)
                s[bq][a] = mfma16(kf[a], qf, z);
        }
        __builtin_amdgcn_s_setprio(0);
    }
    __syncthreads();  // bar3: v^T visible; q/k reads done (R1 writable, R0 scratch ok)

    // ---- softmax + PV per query tile; P via 2KB per-wave LDS scratch in dead R0 ----
    {
        bf16x8 vf[2][2];
        #pragma unroll
        for (int dt = 0; dt < 2; ++dt)
            #pragma unroll
            for (int kt = 0; kt < 2; ++kt)
                vf[dt][kt] = *(const bf16x8*)adr128(R2, h * 32 + dt * 16 + lq, kt * 64 + qd * 16);
        u16* pb = R0 + w * 1024;  // per-wave [16 queries][64 keys] bf16
        const u16* cbb = cbt + ((size_t)((b & (NWIN - 1)) * HH + h) << 12);
        #pragma unroll
        for (int bq = 0; bq < 4; ++bq) {
            uint2 cb2[4];
            #pragma unroll
            for (int a = 0; a < 4; ++a)
                cb2[a] = *(const uint2*)(cbb + (bq * 16 + lq) * 64 + a * 16 + qd * 4);
            #pragma unroll
            for (int a = 0; a < 4; ++a) {
                s[bq][a][0] += b2f((u16)(cb2[a].x & 0xffffu));
                s[bq][a][1] += b2f((u16)(cb2[a].x >> 16));
                s[bq][a][2] += b2f((u16)(cb2[a].y & 0xffffu));
                s[bq][a][3] += b2f((u16)(cb2[a].y >> 16));
            }
            float m0 = s[bq][0][0];
            #pragma unroll
            for (int a = 0; a < 4; ++a)
                #pragma unroll
                for (int r = 0; r < 4; ++r) m0 = fmaxf(m0, s[bq][a][r]);
            m0 = fmaxf(m0, __shfl_xor(m0, 16));
            m0 = fmaxf(m0, __shfl_xor(m0, 32));
            uint2 pk[4];
            float sm = 0.f;
            #pragma unroll
            for (int a = 0; a < 4; ++a) {
                float p0 = __expf(s[bq][a][0] - m0), p1 = __expf(s[bq][a][1] - m0);
                float p2 = __expf(s[bq][a][2] - m0), p3 = __expf(s[bq][a][3] - m0);
                pk[a] = pack4(p0, p1, p2, p3);
                sm += b2f((u16)pk[a].x) + b2f((u16)(pk[a].x >> 16))
                    + b2f((u16)pk[a].y) + b2f((u16)(pk[a].y >> 16));
            }
            sm += __shfl_xor(sm, 16);
            sm += __shfl_xor(sm, 32);
            const float inv = 1.f / sm;
            #pragma unroll
            for (int a = 0; a < 4; ++a)
                *(uint2*)adr128(pb, lq, 32 * a + 8 * qd) = pk[a];
            // fence: same-wave LDS RAW with no intervening __syncthreads —
            // stop the compiler reordering/eliminating the P stores (TBAA) and
            // drain the ds_writes before the b128 reads (rule #18 discipline).
            asm volatile("s_waitcnt lgkmcnt(0)" ::: "memory");
            __builtin_amdgcn_sched_barrier(0);
            f32x4 o[2] = {{0.f,0.f,0.f,0.f},{0.f,0.f,0.f,0.f}};
            __builtin_amdgcn_s_setprio(1);
            #pragma unroll
            for (int kt = 0; kt < 2; ++kt) {
                bf16x8 pf = *(const bf16x8*)adr128(pb, lq, 64 * kt + 16 * qd);
                #pragma unroll
                for (int dt = 0; dt < 2; ++dt)
                    o[dt] = mfma16(vf[dt][kt], pf, o[dt]);
            }
            __builtin_amdgcn_s_setprio(0);
            __builtin_amdgcn_sched_barrier(0);  // keep next bq's P stores below these reads
            #pragma unroll
            for (int dt = 0; dt < 2; ++dt) {
                uint2 px = pack4(o[dt][0] * inv, o[dt][1] * inv,
                                 o[dt][2] * inv, o[dt][3] * inv);
                *(uint2*)adr256(R1, bq * 16 + lq, 64 * h + 32 * dt + 8 * qd) = px;
            }
        }
    }

    // ---- GEMM3: out = x @ pjw + proj_b ----
    {
        bf16x8 bw[2][4];
        #pragma unroll
        for (int n2 = 0; n2 < 2; ++n2)
            #pragma unroll
            for (int kt = 0; kt < 4; ++kt)
                bw[n2][kt] = *(const bf16x8*)(pjwp + (((w + 4 * n2) * 4 + kt) * 64 + lane) * 8);
        __syncthreads();  // bar4: x complete in R1
        f32x4 acc[4][2] = {};
        __builtin_amdgcn_s_setprio(1);
        #pragma unroll
        for (int mt = 0; mt < 4; ++mt) {
            bf16x8 a[4];
            #pragma unroll
            for (int kt = 0; kt < 4; ++kt)
                a[kt] = *(const bf16x8*)adr256(R1, mt * 16 + lq, kt * 64 + qd * 16);
            #pragma unroll
            for (int n2 = 0; n2 < 2; ++n2)
                #pragma unroll
                for (int kt = 0; kt < 4; ++kt)
                    acc[mt][n2] = mfma16(a[kt], bw[n2][kt], acc[mt][n2]);
        }
        __builtin_amdgcn_s_setprio(0);
        float* outb = out + (size_t)b * NN * CC;
        #pragma unroll
        for (int n2 = 0; n2 < 2; ++n2) {
            const int col = 16 * (w + 4 * n2) + lq;
            const float bias = proj_b[col];
            #pragma unroll
            for (int mt = 0; mt < 4; ++mt)
                #pragma unroll
                for (int r = 0; r < 4; ++r) {
                    const int row = mt * 16 + qd * 4 + r;
                    if (row < NN) outb[row * CC + col] = acc[mt][n2][r] + bias;
                }
        }
    }
}

extern "C" void kernel_launch(void* const* d_in, const int* in_sizes, int n_in,
                              void* d_out, int out_size, void* d_ws, size_t ws_size,
                              hipStream_t stream) {
    const float* query      = (const float*)d_in[0];
    const float* source     = (const float*)d_in[1];
    const float* mask       = (const float*)d_in[2];
    const float* q_w        = (const float*)d_in[3];
    const float* q_b        = (const float*)d_in[4];
    const float* kv_w       = (const float*)d_in[5];
    const float* kv_b       = (const float*)d_in[6];
    const float* proj_w     = (const float*)d_in[7];
    const float* proj_b     = (const float*)d_in[8];
    const float* bias_table = (const float*)d_in[9];
    const int*   rel_idx    = (const int*)d_in[10];
    float* out = (float*)d_out;

    u16* cbt   = (u16*)d_ws;              // 1 Mi u16 = 2 MB
    u16* qwp   = cbt + 1048576;           // 16384 u16
    u16* kvwp  = qwp + 16384;             // 32768 u16
    u16* pjwp  = kvwp + 32768;            // 16384 u16
    float* qbs = (float*)(pjwp + 16384);  // 128 f32

    prep_cbt<<<4096, 256, 0, stream>>>(bias_table, rel_idx, mask, cbt);
    prep_w<<<257, 256, 0, stream>>>(q_w, q_b, kv_w, proj_w, qwp, kvwp, pjwp, qbs);
    wmha_main<<<BB, 256, 0, stream>>>(query, source, qwp, kvwp, pjwp, qbs,
                                      kv_b, proj_b, cbt, out);
}